// Round 7
// baseline (3255.391 us; speedup 1.0000x reference)
//
#include <hip/hip_runtime.h>
#include <hip/hip_fp16.h>

// ---------------------------------------------------------------------------
// GraphConv_8847632629923 : round 6
//   GCN tier (the ~2.4 ms tail): k_gemm_node / k_gemm_agg rewritten as
//   64x128 full-N fp32 tiles (32 acc/thread, 3x ds_read_b128 per k-step).
//   fp32 kept deliberately: fp16/bf16 in the z-path risks SAGPool top-k
//   rank flips (score err ~1e-3 vs boundary gaps ~0.05 -> ~10 expected
//   flips). Accumulation order unchanged -> z bitwise identical.
//   k_proj: XCD-aware swizzle so the 8 N-blocks sharing an A-tile land on
//   one XCD's L2 (FETCH was 4x the unique bytes because consecutive blocks
//   round-robin across the 8 XCD L2s).
// ---------------------------------------------------------------------------

#define GB   256          // batch (graphs)
#define SS   200          // nodes per graph
#define KIN  200          // input features
#define HD   128          // hidden
#define NLAY 4
#define NHD  8
#define TOPK 100
#define NT   (GB * SS)    // 51200 nodes
#define EPG_ 6400
#define NE_  (GB * EPG_)  // 1,638,400 edges
#define EMB_ 512

typedef _Float16 half8 __attribute__((ext_vector_type(8)));
typedef _Float16 half4v __attribute__((ext_vector_type(4)));
typedef float floatx4 __attribute__((ext_vector_type(4)));

// ---------------- adjacency build ----------------
__global__ __launch_bounds__(256) void k_build_A(const int* __restrict__ src,
                                                 const int* __restrict__ dst,
                                                 float* __restrict__ A) {
  int e = blockIdx.x * 256 + threadIdx.x;
  if (e >= NE_) return;
  int d = dst[e], s = src[e];
  int b = d / SS;
  int dl = d - b * SS;
  int sl = s - b * SS;
  atomicAdd(&A[((size_t)b * SS + dl) * SS + sl], 1.0f);
}

// ---------------- dinv = rsqrt(in_deg + 1) ----------------
__global__ __launch_bounds__(256) void k_dinv(const float* __restrict__ A,
                                              float* __restrict__ dinv) {
  int node = blockIdx.x * 4 + (threadIdx.x >> 6);
  int lane = threadIdx.x & 63;
  const float* r = A + (size_t)node * SS;
  float v = r[lane] + r[lane + 64] + r[lane + 128];
  if (lane < 8) v += r[lane + 192];
#pragma unroll
  for (int o = 32; o; o >>= 1) v += __shfl_xor(v, o);
  if (lane == 0) dinv[node] = rsqrtf(v + 1.0f);
}

// ------- node GEMM v2: out[N,128] = act([in1|in2] @ W + bias), 64x128 ------
__global__ __launch_bounds__(256) void k_gemm_node(
    const float* __restrict__ in1, int k1,
    const float* __restrict__ in2, int k2,        // optional, stride 128
    const float* __restrict__ W,                  // [k1+k2][128]
    const float* __restrict__ bias,               // [128] or null
    float* __restrict__ out, int doTanh) {
  const int row0 = blockIdx.x * 64;
  const int t  = threadIdx.x;
  const int tx = t & 15, ty = t >> 4;
  const int K = k1 + k2;
  __shared__ __align__(16) float As[32][68];     // [k][m]
  __shared__ __align__(16) float Bs[32][132];    // [k][n], full 128 cols
  float acc[4][8];
#pragma unroll
  for (int i = 0; i < 4; ++i)
#pragma unroll
    for (int j = 0; j < 8; ++j) acc[i][j] = 0.f;

  for (int k0 = 0; k0 < K; k0 += 32) {
    __syncthreads();
#pragma unroll
    for (int p = 0; p < 8; ++p) {               // A: 64x32
      int li = t + p * 256;
      int kk = li & 31, m = li >> 5;
      int kg = k0 + kk;
      int row = row0 + m;
      float v = 0.f;
      if (kg < k1)     v = in1[(size_t)row * k1 + kg];
      else if (kg < K) v = in2[(size_t)row * HD + (kg - k1)];
      As[kk][m] = v;
    }
#pragma unroll
    for (int p = 0; p < 16; ++p) {              // B: 32x128
      int li = t + p * 256;
      int n = li & 127, kb = li >> 7;
      int kg2 = k0 + kb;
      Bs[kb][n] = (kg2 < K) ? W[(size_t)kg2 * HD + n] : 0.f;
    }
    __syncthreads();
#pragma unroll
    for (int kk = 0; kk < 32; ++kk) {
      float4 av = *reinterpret_cast<const float4*>(&As[kk][ty * 4]);
      float4 b0 = *reinterpret_cast<const float4*>(&Bs[kk][tx * 4]);
      float4 b1 = *reinterpret_cast<const float4*>(&Bs[kk][64 + tx * 4]);
      float a[4] = {av.x, av.y, av.z, av.w};
      float w0[4] = {b0.x, b0.y, b0.z, b0.w};
      float w1[4] = {b1.x, b1.y, b1.z, b1.w};
#pragma unroll
      for (int i = 0; i < 4; ++i) {
#pragma unroll
        for (int j = 0; j < 4; ++j) {
          acc[i][j]     += a[i] * w0[j];
          acc[i][4 + j] += a[i] * w1[j];
        }
      }
    }
  }
#pragma unroll
  for (int i = 0; i < 4; ++i) {
    int row = row0 + ty * 4 + i;
    int c0 = tx * 4, c1 = 64 + tx * 4;
    float4 r0, r1;
    r0.x = acc[i][0] + (bias ? bias[c0 + 0] : 0.f);
    r0.y = acc[i][1] + (bias ? bias[c0 + 1] : 0.f);
    r0.z = acc[i][2] + (bias ? bias[c0 + 2] : 0.f);
    r0.w = acc[i][3] + (bias ? bias[c0 + 3] : 0.f);
    r1.x = acc[i][4] + (bias ? bias[c1 + 0] : 0.f);
    r1.y = acc[i][5] + (bias ? bias[c1 + 1] : 0.f);
    r1.z = acc[i][6] + (bias ? bias[c1 + 2] : 0.f);
    r1.w = acc[i][7] + (bias ? bias[c1 + 3] : 0.f);
    if (doTanh) {
      r0.x = tanhf(r0.x); r0.y = tanhf(r0.y); r0.z = tanhf(r0.z); r0.w = tanhf(r0.w);
      r1.x = tanhf(r1.x); r1.y = tanhf(r1.y); r1.z = tanhf(r1.z); r1.w = tanhf(r1.w);
    }
    *reinterpret_cast<float4*>(&out[(size_t)row * HD + c0]) = r0;
    *reinterpret_cast<float4*>(&out[(size_t)row * HD + c1]) = r1;
  }
}

// ------- GCN aggregation v2: x1 = tanh( Â @ xw + b ), 64x128 tiles ---------
__global__ __launch_bounds__(256) void k_gemm_agg(
    const float* __restrict__ A, const float* __restrict__ dinv,
    const float* __restrict__ xw, const float* __restrict__ bias,
    float* __restrict__ out) {
  const int b    = blockIdx.x >> 2;
  const int row0 = (blockIdx.x & 3) * 64;
  const int t  = threadIdx.x;
  const int tx = t & 15, ty = t >> 4;
  const float* Ab = A + (size_t)b * SS * SS;
  const float* dv = dinv + b * SS;
  __shared__ __align__(16) float As[32][68];
  __shared__ __align__(16) float Bs[32][132];
  float acc[4][8];
#pragma unroll
  for (int i = 0; i < 4; ++i)
#pragma unroll
    for (int j = 0; j < 8; ++j) acc[i][j] = 0.f;

  for (int k0 = 0; k0 < SS; k0 += 32) {
    __syncthreads();
#pragma unroll
    for (int p = 0; p < 8; ++p) {
      int li = t + p * 256;
      int kk = li & 31, m = li >> 5;
      int d = row0 + m;
      int sg = k0 + kk;
      float v = 0.f;
      if (d < SS && sg < SS) {
        v = Ab[(size_t)d * SS + sg];
        if (d == sg) v += 1.0f;               // self-loop
        v *= dv[d] * dv[sg];                  // D^-1/2 (A+I) D^-1/2
      }
      As[kk][m] = v;
    }
#pragma unroll
    for (int p = 0; p < 16; ++p) {
      int li = t + p * 256;
      int n = li & 127, kb = li >> 7;
      int sg2 = k0 + kb;
      Bs[kb][n] = (sg2 < SS) ? xw[((size_t)b * SS + sg2) * HD + n] : 0.f;
    }
    __syncthreads();
#pragma unroll
    for (int kk = 0; kk < 32; ++kk) {
      float4 av = *reinterpret_cast<const float4*>(&As[kk][ty * 4]);
      float4 b0 = *reinterpret_cast<const float4*>(&Bs[kk][tx * 4]);
      float4 b1 = *reinterpret_cast<const float4*>(&Bs[kk][64 + tx * 4]);
      float a[4] = {av.x, av.y, av.z, av.w};
      float w0[4] = {b0.x, b0.y, b0.z, b0.w};
      float w1[4] = {b1.x, b1.y, b1.z, b1.w};
#pragma unroll
      for (int i = 0; i < 4; ++i) {
#pragma unroll
        for (int j = 0; j < 4; ++j) {
          acc[i][j]     += a[i] * w0[j];
          acc[i][4 + j] += a[i] * w1[j];
        }
      }
    }
  }
#pragma unroll
  for (int i = 0; i < 4; ++i) {
    int row = row0 + ty * 4 + i;
    if (row >= SS) continue;
    int c0 = tx * 4, c1 = 64 + tx * 4;
    float4 r0, r1;
    r0.x = tanhf(acc[i][0] + bias[c0 + 0]);
    r0.y = tanhf(acc[i][1] + bias[c0 + 1]);
    r0.z = tanhf(acc[i][2] + bias[c0 + 2]);
    r0.w = tanhf(acc[i][3] + bias[c0 + 3]);
    r1.x = tanhf(acc[i][4] + bias[c1 + 0]);
    r1.y = tanhf(acc[i][5] + bias[c1 + 1]);
    r1.z = tanhf(acc[i][6] + bias[c1 + 2]);
    r1.w = tanhf(acc[i][7] + bias[c1 + 3]);
    *reinterpret_cast<float4*>(&out[((size_t)b * SS + row) * HD + c0]) = r0;
    *reinterpret_cast<float4*>(&out[((size_t)b * SS + row) * HD + c1]) = r1;
  }
}

// ---------------- SAGPool: score, top-k select, padded write ----------------
__global__ __launch_bounds__(256) void k_sag(
    const float* __restrict__ z, const float* __restrict__ A,
    const float* __restrict__ w1, const float* __restrict__ w2,
    const float* __restrict__ sb, float* __restrict__ xc, int layer) {
  const int b = blockIdx.x, t = threadIdx.x;
  __shared__ float w1s[HD], w2s[HD];
  __shared__ float zw1[SS], sc[SS], fac[SS];
  if (t < HD) { w1s[t] = w1[t]; w2s[t] = w2[t]; }
  __syncthreads();
  float a2 = 0.f;
  if (t < SS) {
    const float4* zr = reinterpret_cast<const float4*>(&z[((size_t)b * SS + t) * HD]);
    float a1 = 0.f;
#pragma unroll
    for (int q = 0; q < HD / 4; ++q) {
      float4 v = zr[q];
      a1 += v.x * w1s[4 * q] + v.y * w1s[4 * q + 1] + v.z * w1s[4 * q + 2] + v.w * w1s[4 * q + 3];
      a2 += v.x * w2s[4 * q] + v.y * w2s[4 * q + 1] + v.z * w2s[4 * q + 2] + v.w * w2s[4 * q + 3];
    }
    zw1[t] = a1;
  }
  __syncthreads();
  if (t < SS) {
    float s = sb[0] + a2;
    const float4* ar = reinterpret_cast<const float4*>(&A[((size_t)b * SS + t) * SS]);
#pragma unroll 5
    for (int q = 0; q < SS / 4; ++q) {
      float4 v = ar[q];
      s += v.x * zw1[4 * q] + v.y * zw1[4 * q + 1] + v.z * zw1[4 * q + 2] + v.w * zw1[4 * q + 3];
    }
    sc[t] = s;
  }
  __syncthreads();
  if (t < SS) {
    float si = sc[t];
    int cnt = 0;
    for (int j = 0; j < SS; ++j) {
      float sj = sc[j];
      cnt += (sj > si || (sj == si && j < t)) ? 1 : 0;
    }
    fac[t] = (cnt < TOPK) ? tanhf(si) : 0.f;
  }
  __syncthreads();
  for (int idx = t; idx < SS * HD; idx += 256) {
    int row = idx >> 7, c = idx & 127;
    xc[((size_t)b * SS + row) * EMB_ + layer * HD + c] =
        fac[row] * z[((size_t)b * SS + row) * HD + c];
  }
}

// ------------- k_proj (MFMA fp16): QK[N,1024] = xc @ [Wq|Wk]^T + b ----------
// XCD-aware swizzle: the 8 bn-siblings of one A-tile share bx%8 (same XCD).
__global__ __launch_bounds__(256) void k_proj(
    const float* __restrict__ xc, const float* __restrict__ Win,
    const float* __restrict__ bin, __half* __restrict__ QKh) {
  const int bx = blockIdx.x;
  const int bm = ((bx >> 6) << 3) | (bx & 7);   // 0..399, same for 8 siblings
  const int bn = (bx >> 3) & 7;                 // 0..7
  const int m0 = bm * 128, n0 = bn * 128;
  const int t    = threadIdx.x;
  const int wave = t >> 6, lane = t & 63;
  const int col  = lane & 15, quad = lane >> 4;
  const int wm = (wave & 1) * 64;
  const int wn = (wave >> 1) * 64;
  __shared__ __align__(16) _Float16 As[128][72];
  __shared__ __align__(16) _Float16 Bs[128][72];
  floatx4 acc[4][4] = {};
  const int lr = t >> 1;
  const int lk = (t & 1) * 32;

  for (int k0 = 0; k0 < EMB_; k0 += 64) {
    __syncthreads();
    const float4* ga = reinterpret_cast<const float4*>(&xc [(size_t)(m0 + lr) * EMB_ + k0 + lk]);
    const float4* gb = reinterpret_cast<const float4*>(&Win[(size_t)(n0 + lr) * EMB_ + k0 + lk]);
#pragma unroll
    for (int q = 0; q < 8; ++q) {
      float4 va = ga[q];
      half4v ha = {(_Float16)va.x, (_Float16)va.y, (_Float16)va.z, (_Float16)va.w};
      *reinterpret_cast<half4v*>(&As[lr][lk + q * 4]) = ha;
      float4 vb = gb[q];
      half4v hb = {(_Float16)vb.x, (_Float16)vb.y, (_Float16)vb.z, (_Float16)vb.w};
      *reinterpret_cast<half4v*>(&Bs[lr][lk + q * 4]) = hb;
    }
    __syncthreads();
#pragma unroll
    for (int ks = 0; ks < 2; ++ks) {
      half8 af[4], bf[4];
#pragma unroll
      for (int i = 0; i < 4; ++i)
        af[i] = *reinterpret_cast<const half8*>(&As[wm + i * 16 + col][ks * 32 + quad * 8]);
#pragma unroll
      for (int j = 0; j < 4; ++j)
        bf[j] = *reinterpret_cast<const half8*>(&Bs[wn + j * 16 + col][ks * 32 + quad * 8]);
#pragma unroll
      for (int i = 0; i < 4; ++i)
#pragma unroll
        for (int j = 0; j < 4; ++j)
          acc[i][j] = __builtin_amdgcn_mfma_f32_16x16x32_f16(af[i], bf[j], acc[i][j], 0, 0, 0);
    }
  }
#pragma unroll
  for (int j = 0; j < 4; ++j) {
    int c = n0 + wn + j * 16 + col;
    float bb = bin[c];
#pragma unroll
    for (int i = 0; i < 4; ++i) {
      int rbase = m0 + wm + i * 16 + quad * 4;
#pragma unroll
      for (int r = 0; r < 4; ++r)
        QKh[(size_t)(rbase + r) * 1024 + c] = __float2half(acc[i][j][r] + bb);
    }
  }
}

// ------------- k_attn (MFMA): block = (graph, 16-row tile) ------------------
__global__ __launch_bounds__(256) void k_attn(
    const __half* __restrict__ QKh,
    float* __restrict__ cpbuf,          // [B][8][200], pre-zeroed
    float* __restrict__ attn) {         // [B][200][200]
  const int b  = blockIdx.x / 13;
  const int it = blockIdx.x % 13;
  const int i0 = it * 16;
  const int rows = (SS - i0 >= 16) ? 16 : (SS - i0);   // 16 or 8
  const int t    = threadIdx.x;
  const int wave = t >> 6;
  const int lane = t & 63;
  const int col  = lane & 15;
  const int quad = lane >> 4;

  __shared__ __align__(16) _Float16 kS[208][72];
  __shared__ __align__(16) _Float16 qS[16][72];
  __shared__ __align__(16) float    Ss[16][212];

  float am[13];
  int   soff[13];
  int   kmax = 0;
#pragma unroll
  for (int k = 0; k < 13; ++k) {
    int idx = t + (k << 8);
    am[k] = 0.f;
    if (idx < rows * 200) {
      int i = idx / 200;
      soff[k] = idx + 12 * i;
      kmax = k + 1;
    } else soff[k] = 0;
  }

  const size_t gbase = (size_t)b * SS * 1024;

  for (int h = 0; h < NHD; ++h) {
    __syncthreads();
#pragma unroll
    for (int p = 0; p < 7; ++p) {
      int li = t + (p << 8);
      if (li < 1664) {
        int j = li >> 3, c = li & 7;
        float4 v = {0.f, 0.f, 0.f, 0.f};
        if (j < SS) v = *reinterpret_cast<const float4*>(
            &QKh[gbase + (size_t)j * 1024 + 512 + h * 64 + c * 8]);
        *reinterpret_cast<float4*>(&kS[j][c * 8]) = v;
      }
    }
    if (t < 128) {
      int i = t >> 3, c = t & 7;
      int gi = i0 + i;
      float4 v = {0.f, 0.f, 0.f, 0.f};
      if (gi < SS) v = *reinterpret_cast<const float4*>(
          &QKh[gbase + (size_t)gi * 1024 + h * 64 + c * 8]);
      *reinterpret_cast<float4*>(&qS[i][c * 8]) = v;
    }
    __syncthreads();
    half8 a0 = *reinterpret_cast<const half8*>(&qS[col][quad * 8]);
    half8 a1 = *reinterpret_cast<const half8*>(&qS[col][32 + quad * 8]);
#pragma unroll
    for (int m = 0; m < 4; ++m) {
      int jt = wave + m * 4;
      if (jt < 13) {
        const int j0 = jt * 16;
        half8 b0 = *reinterpret_cast<const half8*>(&kS[j0 + col][quad * 8]);
        half8 b1 = *reinterpret_cast<const half8*>(&kS[j0 + col][32 + quad * 8]);
        floatx4 acc = {0.f, 0.f, 0.f, 0.f};
        acc = __builtin_amdgcn_mfma_f32_16x16x32_f16(a0, b0, acc, 0, 0, 0);
        acc = __builtin_amdgcn_mfma_f32_16x16x32_f16(a1, b1, acc, 0, 0, 0);
#pragma unroll
        for (int r = 0; r < 4; ++r)
          Ss[quad * 4 + r][j0 + col] = acc[r] * 0.125f;
      }
    }
    __syncthreads();
#pragma unroll
    for (int ri = 0; ri < 4; ++ri) {
      int r = wave * 4 + ri;
      if (r < rows) {
        float* srow = &Ss[r][0];
        float s0 = srow[lane], s1 = srow[lane + 64], s2 = srow[lane + 128];
        float s3 = (lane < 8) ? srow[lane + 192] : -1e30f;
        float mx = fmaxf(fmaxf(s0, s1), fmaxf(s2, s3));
#pragma unroll
        for (int o = 32; o; o >>= 1) mx = fmaxf(mx, __shfl_xor(mx, o));
        float e0 = __expf(s0 - mx), e1 = __expf(s1 - mx), e2 = __expf(s2 - mx);
        float e3 = (lane < 8) ? __expf(s3 - mx) : 0.f;
        float sum = e0 + e1 + e2 + e3;
#pragma unroll
        for (int o = 32; o; o >>= 1) sum += __shfl_xor(sum, o);
        float rl = 1.0f / sum;
        srow[lane] = e0 * rl; srow[lane + 64] = e1 * rl; srow[lane + 128] = e2 * rl;
        if (lane < 8) srow[lane + 192] = e3 * rl;
      }
    }
    __syncthreads();
    const float* sflat = &Ss[0][0];
#pragma unroll
    for (int k = 0; k < 13; ++k)
      if (k < kmax) am[k] += sflat[soff[k]] * 0.125f;
    if (t < SS) {
      float s = 0.f;
      for (int i = 0; i < rows; ++i) s += Ss[i][t];
      atomicAdd(&cpbuf[((size_t)b * NHD + h) * SS + t], s);
    }
  }
  float* abase = &attn[((size_t)b * SS + i0) * SS];
#pragma unroll
  for (int k = 0; k < 13; ++k)
    if (k < kmax) abase[t + (k << 8)] = am[k];
}

// ------------- k_pool: tvec_h = cp_h^T @ xc ; pooled = Wv tvec + bv*200 -----
__global__ __launch_bounds__(256) void k_pool(
    const float* __restrict__ xc, const float* __restrict__ cpbuf,
    const float* __restrict__ Win, const float* __restrict__ bin,
    float* __restrict__ pooled) {
  const int b = blockIdx.x, t = threadIdx.x;
  __shared__ float cps[NHD][SS];
  __shared__ float tvs[NHD][EMB_];
  for (int idx = t; idx < NHD * SS; idx += 256) {
    int h = idx / SS, j = idx - h * SS;
    cps[h][j] = cpbuf[((size_t)b * NHD + h) * SS + j];
  }
  __syncthreads();
  const float* xcb = xc + (size_t)b * SS * EMB_;
  float a0[NHD] = {0.f}, a1[NHD] = {0.f};
  for (int j = 0; j < SS; ++j) {
    float x0 = xcb[(size_t)j * EMB_ + t];
    float x1 = xcb[(size_t)j * EMB_ + t + 256];
#pragma unroll
    for (int h = 0; h < NHD; ++h) {
      float c = cps[h][j];
      a0[h] += c * x0; a1[h] += c * x1;
    }
  }
#pragma unroll
  for (int h = 0; h < NHD; ++h) { tvs[h][t] = a0[h]; tvs[h][t + 256] = a1[h]; }
  __syncthreads();
  const int wv = t >> 6, lane = t & 63;
  for (int e = wv; e < EMB_; e += 4) {
    int h = e >> 6;
    const float* wr = Win + (size_t)(2 * EMB_ + e) * EMB_;
    float s = 0.f;
#pragma unroll
    for (int q = 0; q < 8; ++q) s += wr[lane + q * 64] * tvs[h][lane + q * 64];
#pragma unroll
    for (int o = 32; o; o >>= 1) s += __shfl_xor(s, o);
    if (lane == 0) pooled[(size_t)b * EMB_ + e] = bin[2 * EMB_ + e] * (float)SS + s;
  }
}

// ---------------- readout ----------------
__global__ __launch_bounds__(256) void k_final(
    const float* __restrict__ pooled, const float* __restrict__ Wout,
    const float* __restrict__ bout, const float* __restrict__ finw,
    const float* __restrict__ finb, float* __restrict__ out) {
  const int b = blockIdx.x, t = threadIdx.x;
  __shared__ float pl[EMB_], po[EMB_];
  for (int k = t; k < EMB_; k += 256) pl[k] = pooled[(size_t)b * EMB_ + k] * (1.0f / (float)SS);
  __syncthreads();
  for (int e = t; e < EMB_; e += 256) {
    const float* wr = &Wout[(size_t)e * EMB_];
    float a = bout[e];
    for (int k = 0; k < EMB_; ++k) a += wr[k] * pl[k];
    po[e] = a;
  }
  __syncthreads();
  if (t < HD) {
    float a = finb[t];
    for (int e = 0; e < EMB_; ++e) a += po[e] * finw[(size_t)e * HD + t];
    out[(size_t)b * HD + t] = tanhf(a);
  }
}

// ---------------------------------------------------------------------------
extern "C" void kernel_launch(void* const* d_in, const int* in_sizes, int n_in,
                              void* d_out, int out_size, void* d_ws, size_t ws_size,
                              hipStream_t stream) {
  const float* x         = (const float*)d_in[0];
  const int*   ei        = (const int*)d_in[1];
  const float* gcn_w0    = (const float*)d_in[4];
  const float* gcn_w     = (const float*)d_in[5];
  const float* gcn_b     = (const float*)d_in[6];
  const float* lin1_w0   = (const float*)d_in[7];
  const float* lin1_w    = (const float*)d_in[8];
  const float* lin1_b    = (const float*)d_in[9];
  const float* lin2_w    = (const float*)d_in[10];
  const float* lin2_b    = (const float*)d_in[11];
  const float* sag_w1    = (const float*)d_in[12];
  const float* sag_w2    = (const float*)d_in[13];
  const float* sag_b     = (const float*)d_in[14];
  const float* mha_in_w  = (const float*)d_in[15];
  const float* mha_in_b  = (const float*)d_in[16];
  const float* mha_out_w = (const float*)d_in[17];
  const float* mha_out_b = (const float*)d_in[18];
  const float* fin_w     = (const float*)d_in[19];
  const float* fin_b     = (const float*)d_in[20];

  float* ws     = (float*)d_ws;
  float* dinv   = ws;                                  // 51,200
  float* Araw   = dinv + NT;                           // 10,240,000
  float* buf0   = Araw + (size_t)GB * SS * SS;         // 6,553,600
  float* buf1   = buf0 + (size_t)NT * HD;              // 6,553,600
  float* zbuf   = buf1 + (size_t)NT * HD;              // 6,553,600
  float* xcbuf  = zbuf + (size_t)NT * HD;              // 26,214,400 (xc)
  float* pooled = xcbuf + (size_t)NT * EMB_;           // 131,072
  // QK (fp16) overlays [Araw .. zbuf-tail) once the GCN layers are done:
  __half* QKh  = (__half*)Araw;                        // 52,428,800 halves
  float* cpbuf = Araw + 26214400;                      // 409,600 floats (tail of overlay)

  float* outp = (float*)d_out;                         // [B,128]
  float* attn = outp + (size_t)GB * HD;                // [B,200,200]

  hipMemsetAsync(Araw, 0, (size_t)GB * SS * SS * sizeof(float), stream);

  k_build_A<<<NE_ / 256, 256, 0, stream>>>(ei, ei + NE_, Araw);
  k_dinv<<<NT / 4, 256, 0, stream>>>(Araw, dinv);

  for (int l = 0; l < NLAY; ++l) {
    const float* zin = (l == 0) ? x : zbuf;
    int k1 = (l == 0) ? KIN : HD;
    const float* gw  = (l == 0) ? gcn_w0  : gcn_w  + (size_t)(l - 1) * HD * HD;
    const float* l1w = (l == 0) ? lin1_w0 : lin1_w + (size_t)(l - 1) * 2 * HD * HD;
    k_gemm_node<<<NT / 64, 256, 0, stream>>>(zin, k1, nullptr, 0, gw, nullptr, buf0, 0);
    k_gemm_agg<<<GB * 4, 256, 0, stream>>>(Araw, dinv, buf0, gcn_b + l * HD, buf1);
    k_gemm_node<<<NT / 64, 256, 0, stream>>>(zin, k1, buf1, HD, l1w, lin1_b + l * HD, buf0, 1);
    k_gemm_node<<<NT / 64, 256, 0, stream>>>(buf0, HD, nullptr, 0,
                                             lin2_w + (size_t)l * HD * HD,
                                             lin2_b + l * HD, zbuf, 1);
    k_sag<<<GB, 256, 0, stream>>>(zbuf, Araw, sag_w1, sag_w2, sag_b, xcbuf, l);
  }

  // ---- MHA ----
  hipMemsetAsync(cpbuf, 0, (size_t)GB * NHD * SS * sizeof(float), stream);
  k_proj<<<(NT / 128) * 8, 256, 0, stream>>>(xcbuf, mha_in_w, mha_in_b, QKh);
  k_attn<<<GB * 13, 256, 0, stream>>>(QKh, cpbuf, attn);
  k_pool<<<GB, 256, 0, stream>>>(xcbuf, cpbuf, mha_in_w, mha_in_b, pooled);
  k_final<<<GB, 256, 0, stream>>>(pooled, mha_out_w, mha_out_b, fin_w, fin_b, outp);
}